// Round 8
// baseline (248.548 us; speedup 1.0000x reference)
//
#include <hip/hip_runtime.h>

// int4-dequant GEMM: y[m,n] = sum_k x[m,k] * scale[n, k/128] * (q[n,k] - 8)
// x: (512,4096) f32 | weight_packed: (11008,2048) int32 (2 nibbles in low byte) |
// scales: (11008,32) f32 | out: (512,11008) f32
//
// R8: split into (1) x->bf16, (2) W dequant->bf16 (memory-bound, no latency
// chain), (3) pure bf16 GEMM in the m97 structure: global_load_lds staging for
// BOTH operands (zero staging regs; R6/R7 showed the reg path serializes),
// XOR-swizzled LDS chunk layout for bank balance, KS=1 (no partials: R7 paid
// 88 MB writes + reduce).

typedef __attribute__((ext_vector_type(8)))  short short8;   // 16x16x32 A/B frag
typedef __attribute__((ext_vector_type(4)))  float f32x4;
typedef __attribute__((ext_vector_type(4)))  int   i32x4;
typedef __attribute__((ext_vector_type(2)))  int   i32x2;
typedef unsigned int   u32;
typedef unsigned short u16;

#define M_DIM 512
#define N_DIM 11008
#define K_DIM 4096
#define BM 128
#define BN 128
#define BK 64
#define THREADS 256

#if defined(__has_builtin)
#  if __has_builtin(__builtin_amdgcn_cvt_pk_bf16_f32)
#    define HAVE_PK_BF16 1
#  endif
#  if __has_builtin(__builtin_amdgcn_global_load_lds)
#    define HAVE_GLLDS 1
#  endif
#endif
#ifndef HAVE_PK_BF16
#  define HAVE_PK_BF16 0
#endif
#ifndef HAVE_GLLDS
#  define HAVE_GLLDS 0
#endif

__device__ __forceinline__ unsigned int fbits(float f) {
    union { float f; unsigned int u; } c; c.f = f; return c.u;
}
__device__ __forceinline__ int pack2bf(float lo, float hi) {  // [hi|lo] bf16, RNE
#if HAVE_PK_BF16
    typedef __attribute__((ext_vector_type(2))) __bf16 bf16x2;
    bf16x2 p = __builtin_amdgcn_cvt_pk_bf16_f32(lo, hi);
    int r; __builtin_memcpy(&r, &p, 4);
    return r;
#else
    unsigned int ul = fbits(lo), uh = fbits(hi);
    unsigned int l = (ul + 0x7FFFu + ((ul >> 16) & 1u)) >> 16;
    unsigned int h = (uh + 0x7FFFu + ((uh >> 16) & 1u)) & 0xFFFF0000u;
    return (int)(h | l);
#endif
}

// 16B global -> LDS direct (HW writes lane's data at ldsbase + lane*16)
__device__ __forceinline__ void async16(const u16* g, u16* lds_wave_base) {
#if HAVE_GLLDS
    __builtin_amdgcn_global_load_lds(
        (const __attribute__((address_space(1))) u32*)g,
        (__attribute__((address_space(3))) u32*)lds_wave_base, 16, 0, 0);
#endif
}

// ---- kernel 1: x f32 -> bf16 ----
__global__ __launch_bounds__(THREADS)
void cvt_x(const float* __restrict__ x, u16* __restrict__ xw)
{
    int idx = (blockIdx.x * THREADS + threadIdx.x) * 4;
    f32x4 v = *(const f32x4*)(x + idx);
    i32x2 p;
    p[0] = pack2bf(v[0], v[1]);
    p[1] = pack2bf(v[2], v[3]);
    *(i32x2*)(xw + idx) = p;
}

// ---- kernel 2: weights int4 -> bf16, row-major (n, k). 1 chunk (4 int32 ->
// 8 bf16) per thread; pure streaming, memory-bound. ----
__global__ __launch_bounds__(THREADS)
void dq_w(const int* __restrict__ wp, const float* __restrict__ scales,
          u16* __restrict__ wb)
{
    size_t ci = (size_t)blockIdx.x * THREADS + threadIdx.x;   // [0, 11008*512)
    int n  = (int)(ci >> 9);
    int jc = (int)(ci & 511);                 // 4-int chunk within row
    float s   = scales[n * 32 + (jc >> 4)];   // 16 chunks per 128-k group
    float ns8 = s * -8.0f;
    i32x4 pv = *(const i32x4*)(wp + ci * 4);
    i32x4 res;
    #pragma unroll
    for (int e = 0; e < 4; ++e) {
        int b = pv[e];
        res[e] = pack2bf((float)(b & 15) * s + ns8,
                         (float)((b >> 4) & 15) * s + ns8);
    }
    *(i32x4*)(wb + ci * 8) = res;
}

// ---- kernel 3: bf16 GEMM, m97 structure. 128x128 tile, 4 waves of 64x64,
// 16x16x32 MFMA. LDS chunk-slot layout: slot(row,kc) = row*8 + (kc ^ (row&7)),
// 16B per slot — XOR balances frag-read banks; staging stays lane-contiguous. ----
__global__ __launch_bounds__(THREADS, 2)
void gemm_bf16(const u16* __restrict__ A,   // (512, 4096) bf16
               const u16* __restrict__ B,   // (11008, 4096) bf16
               float* __restrict__ out)
{
    __shared__ __align__(16) u16 sA[BM * BK];   // 16 KB, slot layout
    __shared__ __align__(16) u16 sB[BN * BK];   // 16 KB

    const int t    = threadIdx.x;
    const int lane = t & 63;
    const int wave = t >> 6;
    const int m0 = blockIdx.x * BM;    // m fastest: 4 blocks share each B n-tile
    const int n0 = blockIdx.y * BN;

    const int wm = (wave & 1) * 64;
    const int wn = (wave >> 1) * 64;
    const int lm   = lane & 15;        // frag row
    const int quad = lane >> 4;        // frag k = quad*8 + j

    f32x4 acc[4][4] = {};

    for (int kb = 0; kb < K_DIM; kb += BK) {
#if HAVE_GLLDS
        // 1024 chunks per matrix, 4 per thread, zero registers
        #pragma unroll
        for (int i = 0; i < 4; ++i) {
            int ci  = i * 256 + t;
            int row = ci >> 3;
            int kc  = (ci & 7) ^ (row & 7);            // global chunk for my slot
            u16* lb = sA + (size_t)(i * 256 + (t >> 6) * 64) * 8;  // wave-uniform
            async16(A + (size_t)(m0 + row) * K_DIM + kb + kc * 8, lb);
        }
        #pragma unroll
        for (int i = 0; i < 4; ++i) {
            int ci  = i * 256 + t;
            int row = ci >> 3;
            int kc  = (ci & 7) ^ (row & 7);
            u16* lb = sB + (size_t)(i * 256 + (t >> 6) * 64) * 8;
            async16(B + (size_t)(n0 + row) * K_DIM + kb + kc * 8, lb);
        }
#else
        #pragma unroll
        for (int i = 0; i < 4; ++i) {
            int ci  = i * 256 + t;
            int row = ci >> 3;
            int kc  = (ci & 7) ^ (row & 7);
            *(i32x4*)(sA + (size_t)ci * 8) =
                *(const i32x4*)(A + (size_t)(m0 + row) * K_DIM + kb + kc * 8);
            *(i32x4*)(sB + (size_t)ci * 8) =
                *(const i32x4*)(B + (size_t)(n0 + row) * K_DIM + kb + kc * 8);
        }
#endif
        __syncthreads();   // compiler inserts vmcnt(0) drain before barrier

        #pragma unroll
        for (int ks = 0; ks < BK; ks += 32) {
            const int kc = (ks >> 3) + quad;
            short8 a[4], b[4];
            #pragma unroll
            for (int i = 0; i < 4; ++i) {
                int row = wm + i * 16 + lm;
                a[i] = *(const short8*)&sA[(row * 8 + (kc ^ (row & 7))) * 8];
            }
            #pragma unroll
            for (int j = 0; j < 4; ++j) {
                int row = wn + j * 16 + lm;
                b[j] = *(const short8*)&sB[(row * 8 + (kc ^ (row & 7))) * 8];
            }
            #pragma unroll
            for (int i = 0; i < 4; ++i)
                #pragma unroll
                for (int j = 0; j < 4; ++j)
                    acc[i][j] = __builtin_amdgcn_mfma_f32_16x16x32_bf16(
                        a[i], b[j], acc[i][j], 0, 0, 0);
        }

        __syncthreads();   // all frag reads done before next tile overwrites
    }

    // epilogue: C/D col(n)=lane&15, row(m)=quad*4+reg
    #pragma unroll
    for (int i = 0; i < 4; ++i) {
        int mg = m0 + wm + i * 16 + quad * 4;
        #pragma unroll
        for (int j = 0; j < 4; ++j) {
            int ng = n0 + wn + j * 16 + lm;
            #pragma unroll
            for (int r = 0; r < 4; ++r)
                out[(size_t)(mg + r) * N_DIM + ng] = acc[i][j][r];
        }
    }
}

// ---- fallback: R7's fused KS=1 kernel (used only if ws too small) ----
#define PAD 8
template<bool PRECVT>
__global__ __launch_bounds__(THREADS, 2)
void dq_gemm_fb(const u16* __restrict__ xw, const float* __restrict__ xf,
                const int* __restrict__ wp, const float* __restrict__ scales,
                float* __restrict__ out)
{
    __shared__ __align__(16) u16 sA[256][BK + PAD];
    __shared__ __align__(16) u16 sB[128][BK + PAD];
    typedef __attribute__((ext_vector_type(16))) float f32x16;

    const int t  = threadIdx.x;
    const int m_idx = blockIdx.x & 1, nb = blockIdx.x >> 1;
    const int m0 = m_idx * 256, n0 = nb * 128;
    const int wave = t >> 6, lane = t & 63;
    const int wm = (wave & 1) * 128, wn = (wave >> 1) * 64;
    const int lr = lane & 31, lk = (lane >> 5) * 8;

    f32x16 acc[4][2] = {};

    for (int kb = 0; kb < K_DIM; kb += BK) {
        const int g = kb >> 7;
        if constexpr (PRECVT) {
            #pragma unroll
            for (int i = 0; i < 8; ++i) {
                int c = i * 256 + t, row = c >> 3, col = (c & 7) * 8;
                *(i32x4*)&sA[row][col] =
                    *(const i32x4*)(xw + (size_t)(m0 + row) * K_DIM + kb + col);
            }
        } else {
            #pragma unroll
            for (int i = 0; i < 16; ++i) {
                int c = i * 256 + t, row = c >> 4, col = (c & 15) * 4;
                f32x4 v = *(const f32x4*)(xf + (size_t)(m0 + row) * K_DIM + kb + col);
                i32x2 p;
                p[0] = pack2bf(v[0], v[1]);
                p[1] = pack2bf(v[2], v[3]);
                *(i32x2*)&sA[row][col] = p;
            }
        }
        #pragma unroll
        for (int i = 0; i < 4; ++i) {
            int c = i * 256 + t, row = c >> 3, ic = (c & 7) * 4;
            i32x4 pv = *(const i32x4*)(wp + (size_t)(n0 + row) * (K_DIM / 2) + (kb >> 1) + ic);
            float s  = scales[(size_t)(n0 + row) * 32 + g];
            float ns8 = s * -8.0f;
            i32x4 res;
            #pragma unroll
            for (int e = 0; e < 4; ++e) {
                int b = pv[e];
                res[e] = pack2bf((float)(b & 15) * s + ns8,
                                 (float)((b >> 4) & 15) * s + ns8);
            }
            *(i32x4*)&sB[row][ic * 2] = res;
        }
        __syncthreads();
        #pragma unroll
        for (int ks = 0; ks < BK; ks += 16) {
            short8 a[4], b[2];
            #pragma unroll
            for (int i = 0; i < 4; ++i)
                a[i] = *(const short8*)&sA[wm + i * 32 + lr][ks + lk];
            #pragma unroll
            for (int j = 0; j < 2; ++j)
                b[j] = *(const short8*)&sB[wn + j * 32 + lr][ks + lk];
            #pragma unroll
            for (int i = 0; i < 4; ++i)
                #pragma unroll
                for (int j = 0; j < 2; ++j)
                    acc[i][j] = __builtin_amdgcn_mfma_f32_32x32x16_bf16(
                        a[i], b[j], acc[i][j], 0, 0, 0);
        }
        __syncthreads();
    }
    const int rbase = (lane >> 5) * 4;
    #pragma unroll
    for (int i = 0; i < 4; ++i) {
        int mg0 = m0 + wm + i * 32 + rbase;
        #pragma unroll
        for (int j = 0; j < 2; ++j) {
            int ng = n0 + wn + j * 32 + lr;
            #pragma unroll
            for (int r = 0; r < 16; ++r)
                out[(size_t)(mg0 + (r & 3) + 8 * (r >> 2)) * N_DIM + ng] = acc[i][j][r];
        }
    }
}

extern "C" void kernel_launch(void* const* d_in, const int* in_sizes, int n_in,
                              void* d_out, int out_size, void* d_ws, size_t ws_size,
                              hipStream_t stream) {
    (void)in_sizes; (void)n_in; (void)out_size;
    const float* x      = (const float*)d_in[0];
    const int*   wpck   = (const int*)d_in[1];
    const float* scales = (const float*)d_in[2];
    float*       out    = (float*)d_out;

    const size_t XW_BYTES = (size_t)M_DIM * K_DIM * 2;        //  4 MB
    const size_t WB_OFF   = XW_BYTES;
    const size_t WB_BYTES = (size_t)N_DIM * K_DIM * 2;        // 90.2 MB

    if (ws_size >= WB_OFF + WB_BYTES) {
        u16* xw = (u16*)d_ws;
        u16* wb = (u16*)((char*)d_ws + WB_OFF);
        cvt_x<<<(M_DIM * K_DIM) / (THREADS * 4), THREADS, 0, stream>>>(x, xw);
        dq_w<<<(int)(((size_t)N_DIM * K_DIM / 8) / THREADS), THREADS, 0, stream>>>(
            wpck, scales, wb);
        dim3 grid(M_DIM / BM, N_DIM / BN);   // (4, 86) = 344
        gemm_bf16<<<grid, dim3(THREADS), 0, stream>>>(xw, wb, out);
    } else if (ws_size >= XW_BYTES) {
        u16* xw = (u16*)d_ws;
        cvt_x<<<(M_DIM * K_DIM) / (THREADS * 4), THREADS, 0, stream>>>(x, xw);
        dq_gemm_fb<true><<<2 * 86, THREADS, 0, stream>>>(xw, x, wpck, scales, out);
    } else {
        dq_gemm_fb<false><<<2 * 86, THREADS, 0, stream>>>(nullptr, x, wpck, scales, out);
    }
}

// Round 9
// 223.449 us; speedup vs baseline: 1.1123x; 1.1123x over previous
//
#include <hip/hip_runtime.h>

// int4-dequant GEMM: y[m,n] = sum_k x[m,k] * scale[n, k/128] * (q[n,k] - 8)
// x: (512,4096) f32 | weight_packed: (11008,2048) int32 (2 nibbles in low byte) |
// scales: (11008,32) f32 | out: (512,11008) f32
//
// R9: FUSED dequant GEMM (R8 showed pre-dequant pays 180MB HBM + 45us for no
// gemm gain; dequant VALU is ~2us/dup chip-wide, not the bottleneck) with the
// real fix: blocks/CU. 128x128 tile, split-K x4 -> 1376 blocks (~3-4 resident/CU
// vs R8's 1.3). A staged via global_load_lds, B loads issued first so dequant
// overlaps A-async flight. XOR-swizzled LDS (R8: 0 conflicts). R7's proven
// coalesced-partials + reduce epilogue (no atomics).

typedef __attribute__((ext_vector_type(8)))  short short8;   // 16x16x32 A/B frag
typedef __attribute__((ext_vector_type(4)))  float f32x4;
typedef __attribute__((ext_vector_type(4)))  int   i32x4;
typedef __attribute__((ext_vector_type(2)))  int   i32x2;
typedef unsigned int   u32;
typedef unsigned short u16;

#define M_DIM 512
#define N_DIM 11008
#define K_DIM 4096
#define BM 128
#define BN 128
#define BK 64
#define KSPLIT 4
#define THREADS 256
#define NTILE_M 4                    // 512/128
#define NTILE_N 86                   // 11008/128
#define NTILES  (NTILE_M * NTILE_N)  // 344
#define TILE_EL (BM * BN)            // 16384

#if defined(__has_builtin)
#  if __has_builtin(__builtin_amdgcn_cvt_pk_bf16_f32)
#    define HAVE_PK_BF16 1
#  endif
#  if __has_builtin(__builtin_amdgcn_global_load_lds)
#    define HAVE_GLLDS 1
#  endif
#endif
#ifndef HAVE_PK_BF16
#  define HAVE_PK_BF16 0
#endif
#ifndef HAVE_GLLDS
#  define HAVE_GLLDS 0
#endif

__device__ __forceinline__ unsigned int fbits(float f) {
    union { float f; unsigned int u; } c; c.f = f; return c.u;
}
__device__ __forceinline__ int pack2bf(float lo, float hi) {  // [hi|lo] bf16, RNE
#if HAVE_PK_BF16
    typedef __attribute__((ext_vector_type(2))) __bf16 bf16x2;
    bf16x2 p = __builtin_amdgcn_cvt_pk_bf16_f32(lo, hi);
    int r; __builtin_memcpy(&r, &p, 4);
    return r;
#else
    unsigned int ul = fbits(lo), uh = fbits(hi);
    unsigned int l = (ul + 0x7FFFu + ((ul >> 16) & 1u)) >> 16;
    unsigned int h = (uh + 0x7FFFu + ((uh >> 16) & 1u)) & 0xFFFF0000u;
    return (int)(h | l);
#endif
}

__device__ __forceinline__ void async16(const u16* g, u16* lds) {
#if HAVE_GLLDS
    __builtin_amdgcn_global_load_lds(
        (const __attribute__((address_space(1))) u32*)g,
        (__attribute__((address_space(3))) u32*)lds, 16, 0, 0);
#endif
}

// ---- x f32 -> bf16 ----
__global__ __launch_bounds__(THREADS)
void cvt_x(const float* __restrict__ x, u16* __restrict__ xw)
{
    int idx = (blockIdx.x * THREADS + threadIdx.x) * 4;
    f32x4 v = *(const f32x4*)(x + idx);
    i32x2 p;
    p[0] = pack2bf(v[0], v[1]);
    p[1] = pack2bf(v[2], v[3]);
    *(i32x2*)(xw + idx) = p;
}

// ---- fused GEMM. LDS slot layout: slot(row,kc) = row*8 + (kc ^ (row&7)),
// 16B (8 bf16) per slot. ----
template<int KS, bool PRECVT>
__global__ __launch_bounds__(THREADS, 2)
void dq_gemm(const u16* __restrict__ xw, const float* __restrict__ xf,
             const int* __restrict__ wp, const float* __restrict__ scales,
             float* __restrict__ out, float* __restrict__ partials)
{
    __shared__ __align__(16) u16 sA[BM * BK];   // 16 KB
    __shared__ __align__(16) u16 sB[BN * BK];   // 16 KB

    const int t    = threadIdx.x;
    const int lane = t & 63;
    const int wave = t >> 6;
    const int bx   = blockIdx.x;

    int m_idx, nb, ksp;
    if (KS == 4) {
        // XCD swizzle: all 4 m-blocks of a given (nb,ksp) share bx&7 (same XCD
        // under %8 round-robin) -> weight tile lives in one L2.
        int x = bx & 7, s = bx >> 3;           // s in [0,172)
        m_idx = s & 3;
        int q = (s >> 2) * 8 + x;              // [0,344)
        ksp = q & 3;
        nb  = q >> 2;
    } else {
        m_idx = bx & 3;
        nb  = bx >> 2;
        ksp = 0;
    }
    const int m0 = m_idx * BM;
    const int n0 = nb * BN;
    const int k0 = ksp * (K_DIM / KS);
    const int KITERS = (K_DIM / KS) / BK;      // 16 (KS=4) / 64 (KS=1)

    const int wm = (wave & 1) * 64;
    const int wn = (wave >> 1) * 64;
    const int lm   = lane & 15;
    const int quad = lane >> 4;

    f32x4 acc[4][4] = {};

    for (int kk = 0; kk < KITERS; ++kk) {
        const int kb = k0 + kk * BK;
        const int g  = kb >> 7;

        // ---- B global loads first (dequant waits only on these) ----
        i32x4 pv[4];
        float sc[4];
        #pragma unroll
        for (int i = 0; i < 4; ++i) {
            int ci = i * 256 + t, row = ci >> 3;
            int kcg = (ci & 7) ^ (row & 7);
            pv[i] = *(const i32x4*)(wp + (size_t)(n0 + row) * (K_DIM / 2) + (kb >> 1) + kcg * 4);
            sc[i] = scales[(size_t)(n0 + row) * 32 + g];
        }

        // ---- A -> LDS async (in flight across B dequant) ----
        if constexpr (PRECVT) {
#if HAVE_GLLDS
            #pragma unroll
            for (int i = 0; i < 4; ++i) {
                int ci = i * 256 + t, row = ci >> 3;
                int kcg = (ci & 7) ^ (row & 7);
                u16* lb = sA + (size_t)(i * 256 + wave * 64) * 8;   // wave-uniform
                async16(xw + (size_t)(m0 + row) * K_DIM + kb + kcg * 8, lb);
            }
#else
            #pragma unroll
            for (int i = 0; i < 4; ++i) {
                int ci = i * 256 + t, row = ci >> 3;
                int kcg = (ci & 7) ^ (row & 7);
                *(i32x4*)(sA + (size_t)ci * 8) =
                    *(const i32x4*)(xw + (size_t)(m0 + row) * K_DIM + kb + kcg * 8);
            }
#endif
        } else {
            #pragma unroll
            for (int i = 0; i < 8; ++i) {
                int c = i * 256 + t;
                int row = c >> 4;                  // 16 f32x4 per 64-k row
                int col4 = (c & 15) * 4;
                int kc = col4 >> 3, half = (col4 >> 2) & 1;
                f32x4 v = *(const f32x4*)(xf + (size_t)(m0 + row) * K_DIM + kb + col4);
                i32x2 p;
                p[0] = pack2bf(v[0], v[1]);
                p[1] = pack2bf(v[2], v[3]);
                *(i32x2*)(sA + (size_t)(row * 8 + (kc ^ (row & 7))) * 8 + half * 4) = p;
            }
        }

        // ---- dequant B -> LDS (overlaps A async flight) ----
        #pragma unroll
        for (int i = 0; i < 4; ++i) {
            int ci = i * 256 + t;
            float s = sc[i], ns8 = s * -8.0f;
            i32x4 res;
            #pragma unroll
            for (int e = 0; e < 4; ++e) {
                int b = pv[i][e];
                res[e] = pack2bf((float)(b & 15) * s + ns8,
                                 (float)((b >> 4) & 15) * s + ns8);
            }
            *(i32x4*)(sB + (size_t)ci * 8) = res;
        }

        __syncthreads();

        #pragma unroll
        for (int ks = 0; ks < BK; ks += 32) {
            const int kc = (ks >> 3) + quad;
            short8 a[4], b[4];
            #pragma unroll
            for (int i = 0; i < 4; ++i) {
                int row = wm + i * 16 + lm;
                a[i] = *(const short8*)&sA[(row * 8 + (kc ^ (row & 7))) * 8];
            }
            #pragma unroll
            for (int j = 0; j < 4; ++j) {
                int row = wn + j * 16 + lm;
                b[j] = *(const short8*)&sB[(row * 8 + (kc ^ (row & 7))) * 8];
            }
            #pragma unroll
            for (int i = 0; i < 4; ++i)
                #pragma unroll
                for (int j = 0; j < 4; ++j)
                    acc[i][j] = __builtin_amdgcn_mfma_f32_16x16x32_bf16(
                        a[i], b[j], acc[i][j], 0, 0, 0);
        }

        __syncthreads();
    }

    if constexpr (KS == 1) {
        // direct store: C/D col(n)=lane&15, row(m)=quad*4+r
        #pragma unroll
        for (int i = 0; i < 4; ++i) {
            int mg = m0 + wm + i * 16 + quad * 4;
            #pragma unroll
            for (int j = 0; j < 4; ++j) {
                int ng = n0 + wn + j * 16 + lm;
                #pragma unroll
                for (int r = 0; r < 4; ++r)
                    out[(size_t)(mg + r) * N_DIM + ng] = acc[i][j][r];
            }
        }
    } else {
        // lane-coalesced partials: float idx = c*1024 + t*4 + r, c = i*4+j
        float* my = partials + ((size_t)(m_idx * NTILE_N + nb) * KS + ksp) * TILE_EL;
        #pragma unroll
        for (int i = 0; i < 4; ++i)
            #pragma unroll
            for (int j = 0; j < 4; ++j)
                *(f32x4*)(my + (i * 4 + j) * 1024 + t * 4) = acc[i][j];
    }
}

// ---- reduce: 688 blocks, block b = m-half h of tile b>>1. Sum 4 partials,
// frag-slot -> row-major via LDS, coalesced writeout. ----
__global__ __launch_bounds__(THREADS)
void reduce_k(const float* __restrict__ partials, float* __restrict__ out)
{
    __shared__ float sT[64][132];     // 33.8 KB

    const int b    = blockIdx.x;
    const int tile = b >> 1;
    const int h    = b & 1;
    const int m_idx = tile / NTILE_N;
    const int nb    = tile % NTILE_N;
    const int m0 = m_idx * BM + h * 64;
    const int n0 = nb * BN;
    const int u  = threadIdx.x;

    const float* base = partials + (size_t)tile * KSPLIT * TILE_EL;

    // phase 1: this half's 2048 f32x4 slots (threads with wave&1==h)
    #pragma unroll
    for (int it = 0; it < 8; ++it) {
        int idx = it * 256 + u;                    // [0,2048)
        int c   = idx >> 7;                        // [0,16)
        int tl  = idx & 127;
        int t   = (tl & 63) | (h << 6) | ((tl >> 6) << 7);
        int off = c * 1024 + t * 4;
        f32x4 s = *(const f32x4*)(base + off);
        s += *(const f32x4*)(base + TILE_EL + off);
        s += *(const f32x4*)(base + 2 * TILE_EL + off);
        s += *(const f32x4*)(base + 3 * TILE_EL + off);
        int i = c >> 2, j = c & 3;
        int lane = t & 63, wave = t >> 6;
        int mrow = i * 16 + (lane >> 4) * 4;       // [0,64) within half
        int ncol = (wave >> 1) * 64 + j * 16 + (lane & 15);
        sT[mrow + 0][ncol] = s[0];
        sT[mrow + 1][ncol] = s[1];
        sT[mrow + 2][ncol] = s[2];
        sT[mrow + 3][ncol] = s[3];
    }
    __syncthreads();

    // phase 2: coalesced row-major writeout
    #pragma unroll
    for (int it = 0; it < 8; ++it) {
        int idx = it * 256 + u;                    // [0,2048)
        int row = idx >> 5;                        // 32 f32x4 per 128-col row
        int c4  = (idx & 31) * 4;
        f32x4 v = *(const f32x4*)&sT[row][c4];
        *(f32x4*)(out + (size_t)(m0 + row) * N_DIM + n0 + c4) = v;
    }
}

extern "C" void kernel_launch(void* const* d_in, const int* in_sizes, int n_in,
                              void* d_out, int out_size, void* d_ws, size_t ws_size,
                              hipStream_t stream) {
    (void)in_sizes; (void)n_in; (void)out_size;
    const float* x      = (const float*)d_in[0];
    const int*   wpck   = (const int*)d_in[1];
    const float* scales = (const float*)d_in[2];
    float*       out    = (float*)d_out;

    const size_t XW_BYTES   = (size_t)M_DIM * K_DIM * 2;                 //  4 MB
    const size_t PART_OFF   = XW_BYTES;
    const size_t PART_BYTES = (size_t)NTILES * KSPLIT * TILE_EL * 4;     // 90.2 MB

    if (ws_size >= PART_OFF + PART_BYTES) {
        u16*   xw   = (u16*)d_ws;
        float* part = (float*)((char*)d_ws + PART_OFF);
        cvt_x<<<(M_DIM * K_DIM) / (THREADS * 4), THREADS, 0, stream>>>(x, xw);
        dq_gemm<KSPLIT, true><<<NTILES * KSPLIT, THREADS, 0, stream>>>(
            xw, x, wpck, scales, out, part);
        reduce_k<<<NTILES * 2, THREADS, 0, stream>>>(part, out);
    } else if (ws_size >= XW_BYTES) {
        u16* xw = (u16*)d_ws;
        cvt_x<<<(M_DIM * K_DIM) / (THREADS * 4), THREADS, 0, stream>>>(x, xw);
        dq_gemm<1, true><<<NTILES, THREADS, 0, stream>>>(
            xw, x, wpck, scales, out, nullptr);
    } else {
        dq_gemm<1, false><<<NTILES, THREADS, 0, stream>>>(
            nullptr, x, wpck, scales, out, nullptr);
    }
}